// Round 5
// baseline (212.623 us; speedup 1.0000x reference)
//
#include <hip/hip_runtime.h>

// LowRankKVCache: out_k[..., :64] = key[..., :64]; out_k[..., 64:] = 0 (same for V).
// Pure memory-bound copy+zero. One float4 (16B) per thread over the full output.
// Row = 128 floats = 32 float4; col4<16 -> copy from input (input row also 32 float4,
// so src index == v), col4>=16 -> zero.
__global__ __launch_bounds__(256) void lowrank_kv_kernel(
    const float4* __restrict__ k_in,
    const float4* __restrict__ v_in,
    float4* __restrict__ out,
    long long n_vec_per_tensor)
{
    long long tid = (long long)blockIdx.x * blockDim.x + threadIdx.x;
    long long total = 2 * n_vec_per_tensor;
    if (tid >= total) return;

    bool is_k = tid < n_vec_per_tensor;
    const float4* __restrict__ src = is_k ? k_in : v_in;
    long long v = is_k ? tid : tid - n_vec_per_tensor;

    int col4 = (int)(v & 31);           // 32 float4 per 128-float row
    float4 val;
    if (col4 < 16) {
        val = src[v];                   // first 64 floats of the row: straight copy
    } else {
        val = make_float4(0.f, 0.f, 0.f, 0.f);
    }
    out[tid] = val;
}

extern "C" void kernel_launch(void* const* d_in, const int* in_sizes, int n_in,
                              void* d_out, int out_size, void* d_ws, size_t ws_size,
                              hipStream_t stream) {
    const float4* k_in = (const float4*)d_in[0];   // key_states   fp32 (4,8,4096,128)
    const float4* v_in = (const float4*)d_in[1];   // value_states fp32 (4,8,4096,128)
    // d_in[2] = cache_position — unused by the reference computation.
    float4* out = (float4*)d_out;                  // k_full ++ v_full, fp32

    long long n_vec = (long long)in_sizes[0] / 4;  // 16,777,216 / 4 = 4,194,304 float4
    long long total = 2 * n_vec;
    const int block = 256;
    unsigned grid = (unsigned)((total + block - 1) / block);
    lowrank_kv_kernel<<<grid, block, 0, stream>>>(k_in, v_in, out, n_vec);
}